// Round 3
// baseline (1240.103 us; speedup 1.0000x reference)
//
#include <hip/hip_runtime.h>
#include <hip/hip_bf16.h>

// Fused InverseResNet. Round 8: N_wave=64 via PURE INTRINSICS (bisect of R7's
// correctness failure). R7 (N=64 with 256 hand-pinned AGPRs + asm MFMAs) failed
// absmax 0.86; all index math re-verified correct, so suspicion falls on the
// asm layer (unguarded VALU->MFMA hazards inside opaque asm, or regalloc vs the
// 256-entry clobber list). This version: same decomposition (4 waves x N=64 x
// M=64; each ds_read_b128 pair feeds 4 MFMAs -> 128KB LDS/phase vs 2048cy MFMA
// -> MFMA-bound), but all weights live in compiler-managed registers
// (bf16x8 wA/wB/wC/wD[16], static indexing) and all MFMAs are intrinsics.
// amdgpu_waves_per_eu(1,1) grants the 512-reg/wave budget so the ~410 live regs
// fit without spill. Compiler owns all hazards/waitcnts.

#define B_TOTAL 65536
#define LATENT  128
#define HIDDEN  256
#define OUTD    128
#define NBLOCKS 4
#define NITER   10
#define MTILE   64
#define LDSP    264   // row stride (elems); 528 B rows, 16B-aligned, b128-read conflict-free

typedef unsigned short u16;
typedef unsigned int   u32;
typedef u16    u16x4  __attribute__((ext_vector_type(4)));
typedef u16    u16x8  __attribute__((ext_vector_type(8)));
typedef __bf16 bf16x8 __attribute__((ext_vector_type(8)));
typedef float  f32x16 __attribute__((ext_vector_type(16)));

__device__ inline u16 f2b(float f){ __bf16 h=(__bf16)f; return __builtin_bit_cast(u16,h); }
__device__ inline float up_lo(u32 u){ return __builtin_bit_cast(float, u<<16); }
__device__ inline float up_hi(u32 u){ return __builtin_bit_cast(float, u & 0xffff0000u); }
__device__ inline u32 pk2(float lo, float hi){ return (u32)f2b(lo) | ((u32)f2b(hi)<<16); }

#define MFMA_I(a,b,c) __builtin_amdgcn_mfma_f32_32x32x16_bf16(a,b,c,0,0,0)

// Weight fragment for the square HIDDENxHIDDEN blocks: 8 k-rows of column col,
// optionally negated (W2 is consumed as -W2 so phase 2 is a pure MFMA-add).
__device__ inline bf16x8 wfrag(const float* __restrict__ W, int krow0, int col, bool neg){
  bf16x8 r;
#pragma unroll
  for (int j=0;j<8;j++){
    float v = W[(size_t)(krow0+j)*HIDDEN + col];
    r[j] = (__bf16)(neg ? -v : v);
  }
  return r;
}

__device__ inline bf16x8 load_wfrag_f(const float* __restrict__ W, int ldw, int krow0,
                                      int col){
  bf16x8 r;
#pragma unroll
  for (int j=0;j<8;j++) r[j] = (__bf16)W[(size_t)(krow0+j)*ldw + col];
  return r;
}

// Store C^T tile to row-major LDS: row = rowbase+lo, cols colbase+8q+4hi+{0..3}.
__device__ inline void store_tile(u16* __restrict__ dst, int row_elem, int colbase, int hi,
                                  const f32x16 a, bool relu){
#pragma unroll
  for (int q=0;q<4;q++){
    u16x4 p;
#pragma unroll
    for (int i=0;i<4;i++){
      float v = a[4*q+i];
      if (relu) v = v > 0.f ? v : 0.f;
      p[i] = f2b(v);
    }
    *(u16x4*)(dst + row_elem + colbase + 8*q + 4*hi) = p;
  }
}

__global__
__attribute__((amdgpu_flat_work_group_size(256,256), amdgpu_waves_per_eu(1,1)))
void irn_kernel(const float* __restrict__ x,
                const float* __restrict__ Winit, const float* __restrict__ binit,
                const float* __restrict__ Wg1,   const float* __restrict__ bg1,
                const float* __restrict__ Wg2,   const float* __restrict__ bg2,
                const float* __restrict__ Wfin,  const float* __restrict__ bfin,
                float* __restrict__ out)
{
  __shared__ u16 Xb[MTILE*LDSP];
  __shared__ u16 Hb[MTILE*LDSP];

  const int tid = threadIdx.x;
  const int wv  = tid >> 6;      // wave 0..3 -> 64-col slice of HIDDEN
  const int ln  = tid & 63;
  const int lo  = ln & 31;
  const int hi  = ln >> 5;
  const int row0 = blockIdx.x * MTILE;
  const int nb   = wv * 64;      // N-slice base (2 x 32-col halves)
  const int colw0 = nb + lo;       // weight col, N-half 0
  const int colw1 = nb + 32 + lo;  // weight col, N-half 1

  // ---- stage x tile [64 x 128] fp32 -> bf16 into Xb (256 threads) ----
  {
    const int r  = tid >> 2;          // 0..63
    const int c0 = (tid & 3) * 32;    // 0,32,64,96
    const float4* src = (const float4*)(x + (size_t)(row0 + r)*LATENT + c0);
    u16* dst = Xb + r*LDSP + c0;
#pragma unroll
    for (int i=0;i<4;i++){
      float4 a = src[i*2], b = src[i*2+1];
      u16x8 p;
      p[0]=f2b(a.x); p[1]=f2b(a.y); p[2]=f2b(a.z); p[3]=f2b(a.w);
      p[4]=f2b(b.x); p[5]=f2b(b.y); p[6]=f2b(b.z); p[7]=f2b(b.w);
      *(u16x8*)(dst + i*8) = p;
    }
  }

  const int rdA0 = lo*LDSP + hi*8;        // activation rows lo / 32+lo
  const int rdA1 = (32+lo)*LDSP + hi*8;

  u32 yp00[8], yp10[8], yp01[8], yp11[8]; // packed bf16x2 y (later y-b2), per tile
  u32 b1p0[8], b1p1[8];                   // packed b1, per N-half

  __syncthreads();

  // ---- initial GEMM: h^T = Winit^T @ x^T (K=128) ----
  {
    bf16x8 wf0[8], wf1[8];
#pragma unroll
    for (int ks=0; ks<8; ks++){
      wf0[ks] = load_wfrag_f(Winit, HIDDEN, ks*16 + hi*8, colw0);
      wf1[ks] = load_wfrag_f(Winit, HIDDEN, ks*16 + hi*8, colw1);
    }
    f32x16 acc00, acc10, acc01, acc11;
#pragma unroll
    for (int r=0;r<16;r++){
      const int cm = (r&3) + 8*(r>>2) + 4*hi;
      float bv0 = binit[nb + cm];
      float bv1 = binit[nb + 32 + cm];
      acc00[r]=bv0; acc10[r]=bv0;
      acc01[r]=bv1; acc11[r]=bv1;
    }
#pragma unroll
    for (int ks=0; ks<8; ks++){
      bf16x8 b0 = *(const bf16x8*)(Xb + rdA0 + ks*16);
      bf16x8 b1 = *(const bf16x8*)(Xb + rdA1 + ks*16);
      acc00=MFMA_I(wf0[ks], b0, acc00);
      acc10=MFMA_I(wf0[ks], b1, acc10);
      acc01=MFMA_I(wf1[ks], b0, acc01);
      acc11=MFMA_I(wf1[ks], b1, acc11);
    }
    __syncthreads();
    store_tile(Xb, (0 +lo)*LDSP, nb,    hi, acc00, false);
    store_tile(Xb, (32+lo)*LDSP, nb,    hi, acc10, false);
    store_tile(Xb, (0 +lo)*LDSP, nb+32, hi, acc01, false);
    store_tile(Xb, (32+lo)*LDSP, nb+32, hi, acc11, false);
#pragma unroll
    for (int i=0;i<8;i++){
      yp00[i] = pk2(acc00[2*i], acc00[2*i+1]);
      yp10[i] = pk2(acc10[2*i], acc10[2*i+1]);
      yp01[i] = pk2(acc01[2*i], acc01[2*i+1]);
      yp11[i] = pk2(acc11[2*i], acc11[2*i+1]);
    }
    __syncthreads();
  }

  // ---- 4 blocks x 10 fixed-point iterations ----
#pragma unroll 1
  for (int b=0; b<NBLOCKS; b++){
    const float* W1p = Wg1 + (size_t)b*HIDDEN*HIDDEN;
    const float* W2p = Wg2 + (size_t)b*HIDDEN*HIDDEN;

    // Per-block weight fragments: W1 (2 col-halves) and -W2 (2 col-halves).
    // Static indexing only (rule: runtime-indexed arrays go to scratch).
    bf16x8 wA[16], wB[16], wC[16], wD[16];
#pragma unroll
    for (int ks=0; ks<16; ks++){
      const int kr = ks*16 + hi*8;
      wA[ks] = wfrag(W1p, kr, colw0, false);
      wB[ks] = wfrag(W1p, kr, colw1, false);
      wC[ks] = wfrag(W2p, kr, colw0, true);
      wD[ks] = wfrag(W2p, kr, colw1, true);
    }

    { // biases: pack b1; fold b2 into packed y (y <- y - b2)
      const float* b1g = bg1 + b*HIDDEN;
      const float* b2g = bg2 + b*HIDDEN;
#pragma unroll
      for (int i=0;i<8;i++){
        const int cm = (2*i&3) + 8*(2*i>>2) + 4*hi;
        const int c0 = nb + cm, c1 = nb + 32 + cm;
        b1p0[i] = pk2(b1g[c0], b1g[c0+1]);
        b1p1[i] = pk2(b1g[c1], b1g[c1+1]);
        yp00[i] = pk2(up_lo(yp00[i]) - b2g[c0], up_hi(yp00[i]) - b2g[c0+1]);
        yp10[i] = pk2(up_lo(yp10[i]) - b2g[c0], up_hi(yp10[i]) - b2g[c0+1]);
        yp01[i] = pk2(up_lo(yp01[i]) - b2g[c1], up_hi(yp01[i]) - b2g[c1+1]);
        yp11[i] = pk2(up_lo(yp11[i]) - b2g[c1], up_hi(yp11[i]) - b2g[c1+1]);
      }
    }

#pragma unroll 1
    for (int it=0; it<NITER; it++){
      { // phase 1: H = relu(X @ W1 + b1)
        f32x16 acc00, acc10, acc01, acc11;
#pragma unroll
        for (int i=0;i<8;i++){
          acc00[2*i]=up_lo(b1p0[i]); acc00[2*i+1]=up_hi(b1p0[i]);
          acc10[2*i]=acc00[2*i];     acc10[2*i+1]=acc00[2*i+1];
          acc01[2*i]=up_lo(b1p1[i]); acc01[2*i+1]=up_hi(b1p1[i]);
          acc11[2*i]=acc01[2*i];     acc11[2*i+1]=acc01[2*i+1];
        }
#pragma unroll
        for (int ks=0; ks<16; ks++){
          bf16x8 b0 = *(const bf16x8*)(Xb + rdA0 + ks*16);
          bf16x8 b1 = *(const bf16x8*)(Xb + rdA1 + ks*16);
          acc00 = MFMA_I(wA[ks], b0, acc00);
          acc10 = MFMA_I(wA[ks], b1, acc10);
          acc01 = MFMA_I(wB[ks], b0, acc01);
          acc11 = MFMA_I(wB[ks], b1, acc11);
        }
        store_tile(Hb, (0 +lo)*LDSP, nb,    hi, acc00, true);
        store_tile(Hb, (32+lo)*LDSP, nb,    hi, acc10, true);
        store_tile(Hb, (0 +lo)*LDSP, nb+32, hi, acc01, true);
        store_tile(Hb, (32+lo)*LDSP, nb+32, hi, acc11, true);
      }
      __syncthreads();
      { // phase 2: Xnew = (y - b2) + H @ (-W2)
        f32x16 acc00, acc10, acc01, acc11;
#pragma unroll
        for (int i=0;i<8;i++){
          acc00[2*i]=up_lo(yp00[i]); acc00[2*i+1]=up_hi(yp00[i]);
          acc10[2*i]=up_lo(yp10[i]); acc10[2*i+1]=up_hi(yp10[i]);
          acc01[2*i]=up_lo(yp01[i]); acc01[2*i+1]=up_hi(yp01[i]);
          acc11[2*i]=up_lo(yp11[i]); acc11[2*i+1]=up_hi(yp11[i]);
        }
#pragma unroll
        for (int ks=0; ks<16; ks++){
          bf16x8 b0 = *(const bf16x8*)(Hb + rdA0 + ks*16);
          bf16x8 b1 = *(const bf16x8*)(Hb + rdA1 + ks*16);
          acc00 = MFMA_I(wC[ks], b0, acc00);
          acc10 = MFMA_I(wC[ks], b1, acc10);
          acc01 = MFMA_I(wD[ks], b0, acc01);
          acc11 = MFMA_I(wD[ks], b1, acc11);
        }
        store_tile(Xb, (0 +lo)*LDSP, nb,    hi, acc00, false);
        store_tile(Xb, (32+lo)*LDSP, nb,    hi, acc10, false);
        store_tile(Xb, (0 +lo)*LDSP, nb+32, hi, acc01, false);
        store_tile(Xb, (32+lo)*LDSP, nb+32, hi, acc11, false);
        if (it == NITER-1){
#pragma unroll
          for (int i=0;i<8;i++){
            yp00[i] = pk2(acc00[2*i], acc00[2*i+1]);
            yp10[i] = pk2(acc10[2*i], acc10[2*i+1]);
            yp01[i] = pk2(acc01[2*i], acc01[2*i+1]);
            yp11[i] = pk2(acc11[2*i], acc11[2*i+1]);
          }
        }
      }
      __syncthreads();
    }
  }

  // ---- final GEMM: out^T = Wfin^T @ X^T ----
  {
    const int mf = wv * 32;         // Wfin col slice (4 waves x 32 = 128)
    bf16x8 wf[16];
#pragma unroll
    for (int ks=0; ks<16; ks++)
      wf[ks] = load_wfrag_f(Wfin, OUTD, ks*16 + hi*8, mf + lo);
    f32x16 acc0, acc1;
#pragma unroll
    for (int r=0;r<16;r++){
      float bv = bfin[mf + (r&3) + 8*(r>>2) + 4*hi];
      acc0[r] = bv; acc1[r] = bv;
    }
#pragma unroll
    for (int ks=0; ks<16; ks++){
      bf16x8 b0 = *(const bf16x8*)(Xb + rdA0 + ks*16);
      bf16x8 b1 = *(const bf16x8*)(Xb + rdA1 + ks*16);
      acc0 = MFMA_I(wf[ks], b0, acc0);
      acc1 = MFMA_I(wf[ks], b1, acc1);
    }
    float* orow0 = out + (size_t)(row0 +      lo)*OUTD;
    float* orow1 = out + (size_t)(row0 + 32 + lo)*OUTD;
#pragma unroll
    for (int q=0;q<4;q++){
      float4 v0 = make_float4(acc0[4*q], acc0[4*q+1], acc0[4*q+2], acc0[4*q+3]);
      float4 v1 = make_float4(acc1[4*q], acc1[4*q+1], acc1[4*q+2], acc1[4*q+3]);
      *(float4*)(orow0 + mf + 8*q + 4*hi) = v0;
      *(float4*)(orow1 + mf + 8*q + 4*hi) = v1;
    }
  }
}

extern "C" void kernel_launch(void* const* d_in, const int* in_sizes, int n_in,
                              void* d_out, int out_size, void* d_ws, size_t ws_size,
                              hipStream_t stream) {
  (void)in_sizes; (void)n_in; (void)d_ws; (void)ws_size; (void)out_size;
  const float* x     = (const float*)d_in[0];
  const float* Winit = (const float*)d_in[1];
  const float* binit = (const float*)d_in[2];
  const float* Wg1   = (const float*)d_in[3];
  const float* bg1   = (const float*)d_in[4];
  const float* Wg2   = (const float*)d_in[5];
  const float* bg2   = (const float*)d_in[6];
  const float* Wfin  = (const float*)d_in[7];
  const float* bfin  = (const float*)d_in[8];
  float* out = (float*)d_out;
  irn_kernel<<<dim3(B_TOTAL/MTILE), dim3(256), 0, stream>>>(
      x, Winit, binit, Wg1, bg1, Wg2, bg2, Wfin, bfin, out);
}

// Round 4
// 1222.607 us; speedup vs baseline: 1.0143x; 1.0143x over previous
//
#include <hip/hip_runtime.h>
#include <hip/hip_bf16.h>

// Fused InverseResNet. Round 9: N_wave=64 with SSA AGPR-pinned weights.
// R8 proved the N=64 decomposition correct but spilled (VGPR_Count=256,
// FETCH 52->182MB scratch traffic): LLVM won't put MFMA A-operand arrays in
// AGPRs on its own. R7's hand-clobber pinning was unsound: clobbers don't
// RESERVE registers, so under pressure the allocator spills compiler values
// into "dead" clobbered AGPRs between asm statements -> weight corruption
// (absmax 0.86). Fix: weights stay SSA values, but an empty asm with "+a"
// constraint forces each frag into the AGPR class; gfx950 MFMA intrinsics read
// AGPR A-operands natively (unified file). Allocator owns liveness -> no
// corruption, no scratch; hazards compiler-managed.
// Structure: 4 waves x N=64 cols x M=64 rows; each ds_read_b128 pair feeds
// 4 MFMAs -> 128KB LDS/phase vs 2048cy MFMA/SIMD -> MFMA-bound.

#define B_TOTAL 65536
#define LATENT  128
#define HIDDEN  256
#define OUTD    128
#define NBLOCKS 4
#define NITER   10
#define MTILE   64
#define LDSP    264   // row stride (elems); 528 B rows, 16B-aligned, b128-read conflict-free

typedef unsigned short u16;
typedef unsigned int   u32;
typedef u16    u16x4  __attribute__((ext_vector_type(4)));
typedef u16    u16x8  __attribute__((ext_vector_type(8)));
typedef u32    u32x4  __attribute__((ext_vector_type(4)));
typedef __bf16 bf16x8 __attribute__((ext_vector_type(8)));
typedef float  f32x16 __attribute__((ext_vector_type(16)));

__device__ inline u16 f2b(float f){ __bf16 h=(__bf16)f; return __builtin_bit_cast(u16,h); }
__device__ inline float up_lo(u32 u){ return __builtin_bit_cast(float, u<<16); }
__device__ inline float up_hi(u32 u){ return __builtin_bit_cast(float, u & 0xffff0000u); }
__device__ inline u32 pk2(float lo, float hi){ return (u32)f2b(lo) | ((u32)f2b(hi)<<16); }

#define MFMA_I(a,b,c) __builtin_amdgcn_mfma_f32_32x32x16_bf16(a,b,c,0,0,0)

// Force a weight fragment into the AGPR register class (SSA-safe pinning).
// Empty asm, "+a" ties the value to an AGPR quad at this point; the MFMA
// intrinsic consumes AGPR operands directly so no copy-back is required.
__device__ inline void pin_a(bf16x8 &v){
  u32x4 t = __builtin_bit_cast(u32x4, v);
  asm("" : "+a"(t));
  v = __builtin_bit_cast(bf16x8, t);
}

// Weight fragment for the square HIDDENxHIDDEN blocks: 8 k-rows of column col,
// optionally negated (W2 is consumed as -W2 so phase 2 is a pure MFMA-add).
__device__ inline bf16x8 wfrag(const float* __restrict__ W, int krow0, int col, bool neg){
  bf16x8 r;
#pragma unroll
  for (int j=0;j<8;j++){
    float v = W[(size_t)(krow0+j)*HIDDEN + col];
    r[j] = (__bf16)(neg ? -v : v);
  }
  return r;
}

__device__ inline bf16x8 load_wfrag_f(const float* __restrict__ W, int ldw, int krow0,
                                      int col){
  bf16x8 r;
#pragma unroll
  for (int j=0;j<8;j++) r[j] = (__bf16)W[(size_t)(krow0+j)*ldw + col];
  return r;
}

// Store C^T tile to row-major LDS: row = rowbase+lo, cols colbase+8q+4hi+{0..3}.
__device__ inline void store_tile(u16* __restrict__ dst, int row_elem, int colbase, int hi,
                                  const f32x16 a, bool relu){
#pragma unroll
  for (int q=0;q<4;q++){
    u16x4 p;
#pragma unroll
    for (int i=0;i<4;i++){
      float v = a[4*q+i];
      if (relu) v = v > 0.f ? v : 0.f;
      p[i] = f2b(v);
    }
    *(u16x4*)(dst + row_elem + colbase + 8*q + 4*hi) = p;
  }
}

__global__
__attribute__((amdgpu_flat_work_group_size(256,256), amdgpu_waves_per_eu(1,1)))
void irn_kernel(const float* __restrict__ x,
                const float* __restrict__ Winit, const float* __restrict__ binit,
                const float* __restrict__ Wg1,   const float* __restrict__ bg1,
                const float* __restrict__ Wg2,   const float* __restrict__ bg2,
                const float* __restrict__ Wfin,  const float* __restrict__ bfin,
                float* __restrict__ out)
{
  __shared__ u16 Xb[MTILE*LDSP];
  __shared__ u16 Hb[MTILE*LDSP];

  const int tid = threadIdx.x;
  const int wv  = tid >> 6;      // wave 0..3 -> 64-col slice of HIDDEN
  const int ln  = tid & 63;
  const int lo  = ln & 31;
  const int hi  = ln >> 5;
  const int row0 = blockIdx.x * MTILE;
  const int nb   = wv * 64;      // N-slice base (2 x 32-col halves)
  const int colw0 = nb + lo;       // weight col, N-half 0
  const int colw1 = nb + 32 + lo;  // weight col, N-half 1

  // ---- stage x tile [64 x 128] fp32 -> bf16 into Xb (256 threads) ----
  {
    const int r  = tid >> 2;          // 0..63
    const int c0 = (tid & 3) * 32;    // 0,32,64,96
    const float4* src = (const float4*)(x + (size_t)(row0 + r)*LATENT + c0);
    u16* dst = Xb + r*LDSP + c0;
#pragma unroll
    for (int i=0;i<4;i++){
      float4 a = src[i*2], b = src[i*2+1];
      u16x8 p;
      p[0]=f2b(a.x); p[1]=f2b(a.y); p[2]=f2b(a.z); p[3]=f2b(a.w);
      p[4]=f2b(b.x); p[5]=f2b(b.y); p[6]=f2b(b.z); p[7]=f2b(b.w);
      *(u16x8*)(dst + i*8) = p;
    }
  }

  const int rdA0 = lo*LDSP + hi*8;        // activation rows lo / 32+lo
  const int rdA1 = (32+lo)*LDSP + hi*8;

  u32 yp00[8], yp10[8], yp01[8], yp11[8]; // packed bf16x2 y (later y-b2), per tile
  u32 b1p0[8], b1p1[8];                   // packed b1, per N-half

  __syncthreads();

  // ---- initial GEMM: h^T = Winit^T @ x^T (K=128) ----
  {
    bf16x8 wf0[8], wf1[8];
#pragma unroll
    for (int ks=0; ks<8; ks++){
      wf0[ks] = load_wfrag_f(Winit, HIDDEN, ks*16 + hi*8, colw0);
      wf1[ks] = load_wfrag_f(Winit, HIDDEN, ks*16 + hi*8, colw1);
    }
    f32x16 acc00, acc10, acc01, acc11;
#pragma unroll
    for (int r=0;r<16;r++){
      const int cm = (r&3) + 8*(r>>2) + 4*hi;
      float bv0 = binit[nb + cm];
      float bv1 = binit[nb + 32 + cm];
      acc00[r]=bv0; acc10[r]=bv0;
      acc01[r]=bv1; acc11[r]=bv1;
    }
#pragma unroll
    for (int ks=0; ks<8; ks++){
      bf16x8 b0 = *(const bf16x8*)(Xb + rdA0 + ks*16);
      bf16x8 b1 = *(const bf16x8*)(Xb + rdA1 + ks*16);
      acc00=MFMA_I(wf0[ks], b0, acc00);
      acc10=MFMA_I(wf0[ks], b1, acc10);
      acc01=MFMA_I(wf1[ks], b0, acc01);
      acc11=MFMA_I(wf1[ks], b1, acc11);
    }
    __syncthreads();
    store_tile(Xb, (0 +lo)*LDSP, nb,    hi, acc00, false);
    store_tile(Xb, (32+lo)*LDSP, nb,    hi, acc10, false);
    store_tile(Xb, (0 +lo)*LDSP, nb+32, hi, acc01, false);
    store_tile(Xb, (32+lo)*LDSP, nb+32, hi, acc11, false);
#pragma unroll
    for (int i=0;i<8;i++){
      yp00[i] = pk2(acc00[2*i], acc00[2*i+1]);
      yp10[i] = pk2(acc10[2*i], acc10[2*i+1]);
      yp01[i] = pk2(acc01[2*i], acc01[2*i+1]);
      yp11[i] = pk2(acc11[2*i], acc11[2*i+1]);
    }
    __syncthreads();
  }

  // ---- 4 blocks x 10 fixed-point iterations ----
#pragma unroll 1
  for (int b=0; b<NBLOCKS; b++){
    const float* W1p = Wg1 + (size_t)b*HIDDEN*HIDDEN;
    const float* W2p = Wg2 + (size_t)b*HIDDEN*HIDDEN;

    // Per-block weight fragments: W1 (2 col-halves) and -W2 (2 col-halves),
    // each pinned into the AGPR class (64 frags = 256 AGPRs).
    bf16x8 wA[16], wB[16], wC[16], wD[16];
#pragma unroll
    for (int ks=0; ks<16; ks++){
      const int kr = ks*16 + hi*8;
      wA[ks] = wfrag(W1p, kr, colw0, false); pin_a(wA[ks]);
      wB[ks] = wfrag(W1p, kr, colw1, false); pin_a(wB[ks]);
      wC[ks] = wfrag(W2p, kr, colw0, true);  pin_a(wC[ks]);
      wD[ks] = wfrag(W2p, kr, colw1, true);  pin_a(wD[ks]);
    }

    { // biases: pack b1; fold b2 into packed y (y <- y - b2)
      const float* b1g = bg1 + b*HIDDEN;
      const float* b2g = bg2 + b*HIDDEN;
#pragma unroll
      for (int i=0;i<8;i++){
        const int cm = (2*i&3) + 8*(2*i>>2) + 4*hi;
        const int c0 = nb + cm, c1 = nb + 32 + cm;
        b1p0[i] = pk2(b1g[c0], b1g[c0+1]);
        b1p1[i] = pk2(b1g[c1], b1g[c1+1]);
        yp00[i] = pk2(up_lo(yp00[i]) - b2g[c0], up_hi(yp00[i]) - b2g[c0+1]);
        yp10[i] = pk2(up_lo(yp10[i]) - b2g[c0], up_hi(yp10[i]) - b2g[c0+1]);
        yp01[i] = pk2(up_lo(yp01[i]) - b2g[c1], up_hi(yp01[i]) - b2g[c1+1]);
        yp11[i] = pk2(up_lo(yp11[i]) - b2g[c1], up_hi(yp11[i]) - b2g[c1+1]);
      }
    }

#pragma unroll 1
    for (int it=0; it<NITER; it++){
      { // phase 1: H = relu(X @ W1 + b1)
        f32x16 acc00, acc10, acc01, acc11;
#pragma unroll
        for (int i=0;i<8;i++){
          acc00[2*i]=up_lo(b1p0[i]); acc00[2*i+1]=up_hi(b1p0[i]);
          acc10[2*i]=acc00[2*i];     acc10[2*i+1]=acc00[2*i+1];
          acc01[2*i]=up_lo(b1p1[i]); acc01[2*i+1]=up_hi(b1p1[i]);
          acc11[2*i]=acc01[2*i];     acc11[2*i+1]=acc01[2*i+1];
        }
#pragma unroll
        for (int ks=0; ks<16; ks++){
          bf16x8 b0 = *(const bf16x8*)(Xb + rdA0 + ks*16);
          bf16x8 b1 = *(const bf16x8*)(Xb + rdA1 + ks*16);
          acc00 = MFMA_I(wA[ks], b0, acc00);
          acc10 = MFMA_I(wA[ks], b1, acc10);
          acc01 = MFMA_I(wB[ks], b0, acc01);
          acc11 = MFMA_I(wB[ks], b1, acc11);
        }
        store_tile(Hb, (0 +lo)*LDSP, nb,    hi, acc00, true);
        store_tile(Hb, (32+lo)*LDSP, nb,    hi, acc10, true);
        store_tile(Hb, (0 +lo)*LDSP, nb+32, hi, acc01, true);
        store_tile(Hb, (32+lo)*LDSP, nb+32, hi, acc11, true);
      }
      __syncthreads();
      { // phase 2: Xnew = (y - b2) + H @ (-W2)
        f32x16 acc00, acc10, acc01, acc11;
#pragma unroll
        for (int i=0;i<8;i++){
          acc00[2*i]=up_lo(yp00[i]); acc00[2*i+1]=up_hi(yp00[i]);
          acc10[2*i]=up_lo(yp10[i]); acc10[2*i+1]=up_hi(yp10[i]);
          acc01[2*i]=up_lo(yp01[i]); acc01[2*i+1]=up_hi(yp01[i]);
          acc11[2*i]=up_lo(yp11[i]); acc11[2*i+1]=up_hi(yp11[i]);
        }
#pragma unroll
        for (int ks=0; ks<16; ks++){
          bf16x8 b0 = *(const bf16x8*)(Hb + rdA0 + ks*16);
          bf16x8 b1 = *(const bf16x8*)(Hb + rdA1 + ks*16);
          acc00 = MFMA_I(wC[ks], b0, acc00);
          acc10 = MFMA_I(wC[ks], b1, acc10);
          acc01 = MFMA_I(wD[ks], b0, acc01);
          acc11 = MFMA_I(wD[ks], b1, acc11);
        }
        store_tile(Xb, (0 +lo)*LDSP, nb,    hi, acc00, false);
        store_tile(Xb, (32+lo)*LDSP, nb,    hi, acc10, false);
        store_tile(Xb, (0 +lo)*LDSP, nb+32, hi, acc01, false);
        store_tile(Xb, (32+lo)*LDSP, nb+32, hi, acc11, false);
        if (it == NITER-1){
#pragma unroll
          for (int i=0;i<8;i++){
            yp00[i] = pk2(acc00[2*i], acc00[2*i+1]);
            yp10[i] = pk2(acc10[2*i], acc10[2*i+1]);
            yp01[i] = pk2(acc01[2*i], acc01[2*i+1]);
            yp11[i] = pk2(acc11[2*i], acc11[2*i+1]);
          }
        }
      }
      __syncthreads();
    }
  }

  // ---- final GEMM: out^T = Wfin^T @ X^T ----
  {
    const int mf = wv * 32;         // Wfin col slice (4 waves x 32 = 128)
    bf16x8 wf[16];
#pragma unroll
    for (int ks=0; ks<16; ks++)
      wf[ks] = load_wfrag_f(Wfin, OUTD, ks*16 + hi*8, mf + lo);
    f32x16 acc0, acc1;
#pragma unroll
    for (int r=0;r<16;r++){
      float bv = bfin[mf + (r&3) + 8*(r>>2) + 4*hi];
      acc0[r] = bv; acc1[r] = bv;
    }
#pragma unroll
    for (int ks=0; ks<16; ks++){
      bf16x8 b0 = *(const bf16x8*)(Xb + rdA0 + ks*16);
      bf16x8 b1 = *(const bf16x8*)(Xb + rdA1 + ks*16);
      acc0 = MFMA_I(wf[ks], b0, acc0);
      acc1 = MFMA_I(wf[ks], b1, acc1);
    }
    float* orow0 = out + (size_t)(row0 +      lo)*OUTD;
    float* orow1 = out + (size_t)(row0 + 32 + lo)*OUTD;
#pragma unroll
    for (int q=0;q<4;q++){
      float4 v0 = make_float4(acc0[4*q], acc0[4*q+1], acc0[4*q+2], acc0[4*q+3]);
      float4 v1 = make_float4(acc1[4*q], acc1[4*q+1], acc1[4*q+2], acc1[4*q+3]);
      *(float4*)(orow0 + mf + 8*q + 4*hi) = v0;
      *(float4*)(orow1 + mf + 8*q + 4*hi) = v1;
    }
  }
}

extern "C" void kernel_launch(void* const* d_in, const int* in_sizes, int n_in,
                              void* d_out, int out_size, void* d_ws, size_t ws_size,
                              hipStream_t stream) {
  (void)in_sizes; (void)n_in; (void)d_ws; (void)ws_size; (void)out_size;
  const float* x     = (const float*)d_in[0];
  const float* Winit = (const float*)d_in[1];
  const float* binit = (const float*)d_in[2];
  const float* Wg1   = (const float*)d_in[3];
  const float* bg1   = (const float*)d_in[4];
  const float* Wg2   = (const float*)d_in[5];
  const float* bg2   = (const float*)d_in[6];
  const float* Wfin  = (const float*)d_in[7];
  const float* bfin  = (const float*)d_in[8];
  float* out = (float*)d_out;
  irn_kernel<<<dim3(B_TOTAL/MTILE), dim3(256), 0, stream>>>(
      x, Winit, binit, Wg1, bg1, Wg2, bg2, Wfin, bfin, out);
}